// Round 9
// baseline (62.927 us; speedup 1.0000x reference)
//
#include <hip/hip_runtime.h>
#include <math.h>

// DTW loss: B=64, N=512, D=2, L1. Wave64 per batch, lane j owns cols [8j,8j+8).
// Round-9: R8's 2-row macro with the a/b chains INTERLEAVED IN SOURCE.
// Model (fits R2-R8): wall = non-overlapped chain ops x 12.2cy; in-order issue
// fills stalls only with ops emitted between chain ops. R8 emitted a-chain
// then b-chain serially -> 34x12.2=414cy/macro. Interleaved order
// (a0,a1,b0,a2,b1,...,a7,b6,b7) keeps the carried cycle at ~17 ops
// (a-chain+dpp) while advancing 2 rows -> ~104cy/row target.

typedef float f32x2 __attribute__((ext_vector_type(2)));
typedef float f32x4 __attribute__((ext_vector_type(4)));

constexpr int NSEQ  = 512;
constexpr int BATCH = 64;
constexpr int LANES = 64;
constexpr int P     = 8;
constexpr int FRONT = 63;     // front pad in float4 row-pairs (m-j >= -63)
constexpr int XS4N  = 384;    // 63 front + 256 valid + 65 back

__device__ __forceinline__ float dpp_shr1_inf(float v) {
    // lane i <- lane i-1; lane 0 <- +inf (bound_ctrl=false)
    int r = __builtin_amdgcn_update_dpp(0x7F800000, __float_as_int(v),
                                        0x138, 0xF, 0xF, false);
    return __int_as_float(r);
}
__device__ __forceinline__ f32x2 pk_add(f32x2 a, f32x2 b) {
    f32x2 d;
    asm("v_pk_add_f32 %0, %1, %2" : "=v"(d) : "v"(a), "v"(b));
    return d;
}

__global__ __launch_bounds__(LANES) void dtw_fused(
    const float* __restrict__ pred,    // (B, N, 2) rows (x)
    const float* __restrict__ target,  // (B, N, 2) cols (y)
    float* __restrict__ out,
    float* __restrict__ ws)            // [0..63] per_batch, [64] flag
{
    const int b = blockIdx.x;
    const int j = threadIdx.x;

    __shared__ f32x4 xs4[XS4N];        // one entry = one ROW PAIR (2x float2)

    const f32x4* pred4 = reinterpret_cast<const f32x4*>(pred) + b * (NSEQ / 2);
    #pragma unroll
    for (int t = 0; t < 4; ++t)
        xs4[FRONT + t * LANES + j] = pred4[t * LANES + j];
    if (j < FRONT) xs4[j] = f32x4{0.f, 0.f, 0.f, 0.f};
    xs4[FRONT + 256 + j] = f32x4{0.f, 0.f, 0.f, 0.f};
    if (j == 0) xs4[383] = f32x4{0.f, 0.f, 0.f, 0.f};

    f32x2 nY[P];
    #pragma unroll
    for (int c = 0; c < P; ++c) {
        const f32x2 y = reinterpret_cast<const f32x2*>(target)[b * NSEQ + j * P + c];
        nY[c].x = -y.x; nY[c].y = -y.y;
    }
    __syncthreads();   // only barrier

    const float INF = __builtin_inff();
    float p[P], q[P], aA[P], aB[P];
    float dg = INF;    // dgA for next macro = leftB of previous macro

    // ---- peeled macro 0: rows 0,1 (lane 0 real; others all-INF via algebra)
    f32x4 x0 = xs4[FRONT - j];
    f32x4 xc1 = xs4[FRONT + 1 - j];
    f32x4 xc2 = xs4[FRONT + 2 - j];
    {
        const f32x2 xa = {x0.x, x0.y}, xb = {x0.z, x0.w};
        const float lA0 = (j == 0) ? 0.0f : INF;
        { const f32x2 d = pk_add(xa, nY[0]); aA[0] = fabsf(d.x) + fabsf(d.y) + lA0; }
        #pragma unroll
        for (int c = 1; c < P; ++c) {
            const f32x2 d = pk_add(xa, nY[c]);
            aA[c] = fabsf(d.x) + fabsf(d.y) + aA[c - 1];        // row-0 cumsum
        }
        { const f32x2 d = pk_add(xb, nY[0]); p[0] = fabsf(d.x) + fabsf(d.y) + aA[0]; }
        #pragma unroll
        for (int c = 1; c < P; ++c) {
            const f32x2 d = pk_add(xb, nY[c]);
            p[c] = fabsf(d.x) + fabsf(d.y)
                 + fminf(fminf(aA[c], aA[c - 1]), p[c - 1]);
        }
    }

    // macro: reads prev-b pb[], prev-a ain[] (dpp only); writes ob[], aout[].
    // a-row: aout[c] = cA[c] + min3(pb[c], c?pb[c-1]:dg, c?aout[c-1]:lA)
    // b-row: ob[c]   = cB[c] + min3(aout[c], c?aout[c-1]:lA, c?ob[c-1]:lB)
    // INTERLEAVED emission: a0,a1,b0,a2,b1,...,a7,b6,b7.
    auto macro = [&](const float (&pb)[P], float (&ob)[P],
                     const float (&ain)[P], float (&aout)[P], f32x4 x4) {
        const f32x2 xa = {x4.x, x4.y}, xb = {x4.z, x4.w};
        float cA[P], cB[P];
        #pragma unroll
        for (int c = 0; c < P; ++c) {
            const f32x2 da = pk_add(xa, nY[c]);
            cA[c] = fabsf(da.x) + fabsf(da.y);
            const f32x2 db = pk_add(xb, nY[c]);
            cB[c] = fabsf(db.x) + fabsf(db.y);
        }
        const float lA = dpp_shr1_inf(ain[P - 1]);
        const float lB = dpp_shr1_inf(pb[P - 1]);

        aout[0] = cA[0] + fminf(fminf(pb[0], dg), lA);                    // a0
        aout[1] = cA[1] + fminf(fminf(pb[1], pb[0]), aout[0]);            // a1
        ob[0]   = cB[0] + fminf(fminf(aout[0], lA), lB);                  // b0
        #pragma unroll
        for (int c = 2; c < P; ++c) {
            aout[c]   = cA[c] + fminf(fminf(pb[c], pb[c - 1]), aout[c - 1]);   // a_c
            ob[c - 1] = cB[c - 1]
                      + fminf(fminf(aout[c - 1], aout[c - 2]), ob[c - 2]);     // b_{c-1}
        }
        ob[P - 1] = cB[P - 1]
                  + fminf(fminf(aout[P - 1], aout[P - 2]), ob[P - 2]);         // b7
        dg = lB;
    };

    // 159 pairs cover macros m = 1..318; 1-pair-deep x prefetch.
    #pragma unroll 2
    for (int mm = 0; mm < 159; ++mm) {
        const int m1 = 1 + 2 * mm;
        const f32x4 xn1 = xs4[FRONT + m1 + 2 - j];
        const f32x4 xn2 = xs4[FRONT + m1 + 3 - j];
        macro(p, q, aA, aB, xc1);    // macro m1
        macro(q, p, aB, aA, xc2);    // macro m1+1
        xc1 = xn1; xc2 = xn2;
    }

    // ---- fused mean reduction (last block to finish) ----
    float* per_batch = ws;
    unsigned* flag = reinterpret_cast<unsigned*>(ws + BATCH);
    if (j == LANES - 1) per_batch[b] = p[P - 1];   // D[511][511]
    __threadfence();
    unsigned old = 0;
    if (j == 0) old = atomicAdd(flag, 1u);
    old = __shfl(old, 0);
    if (old == BATCH - 1) {
        __threadfence();
        float v = per_batch[j];
        #pragma unroll
        for (int off = 32; off >= 1; off >>= 1) v += __shfl_down(v, off);
        if (j == 0) out[0] = v * (1.0f / BATCH);
    }
}

extern "C" void kernel_launch(void* const* d_in, const int* in_sizes, int n_in,
                              void* d_out, int out_size, void* d_ws, size_t ws_size,
                              hipStream_t stream) {
    const float* pred   = (const float*)d_in[0];
    const float* target = (const float*)d_in[1];
    float* out = (float*)d_out;
    float* ws  = (float*)d_ws;

    hipMemsetAsync((char*)d_ws + BATCH * sizeof(float), 0, sizeof(unsigned), stream);
    dtw_fused<<<BATCH, LANES, 0, stream>>>(pred, target, out, ws);
}